// Round 9
// baseline (65.337 us; speedup 1.0000x reference)
//
#include <hip/hip_runtime.h>

// Dist_Conv2D — R9: MEASUREMENT PROBE (intentionally 8x work).
// R8 falsified VALU-throughput binding (-22% instrs -> +5% time); all latency
// levers were null too. We need the kernel's own rocprof counters, but at
// ~13.5us it never makes top-5 (38us harness fills win). This round repeats
// the computation 8x inside the dispatch: repeat r handles filter chunk
// (fc+r)&15, so every output is written with correct values (8 redundant
// identical writers per slice — deterministic, passes validation) and the
// dispatch lasts ~100us -> top of rocprof -> real VALUBusy/Occupancy/FETCH.
// Next round reverts to single-pass using what this reveals.

#define BB 4
#define CC 16
#define HH 64
#define WW 64
#define FF 64
#define FCHUNK 4
#define REP 8

#define DPP_LEFT(v)  __int_as_float(__builtin_amdgcn_update_dpp(            \
        __float_as_int(v), __float_as_int(v), 0x138, 0xf, 0xf, false))
#define DPP_RIGHT(v) __int_as_float(__builtin_amdgcn_update_dpp(            \
        __float_as_int(v), __float_as_int(v), 0x130, 0xf, 0xf, false))

__global__ __launch_bounds__(256) void dist_conv2d_kernel(
    const float* __restrict__ x,
    const float* __restrict__ wgt,
    const float* __restrict__ bias,
    float* __restrict__ out) {
    // block = 256 threads = (h_lo(2) | w(6)); blockIdx bits: fc(4)|b(2)|h_hi(4)
    int w  = threadIdx.x & 63;             // lane id
    int h  = ((blockIdx.x & 15) << 2) | (threadIdx.x >> 6);
    int b  = (blockIdx.x >> 4) & 3;        // SGPR
    int fc = blockIdx.x >> 6;              // SGPR, 0..15

    // replicate-pad clamped row indices (columns via DPP boundary rule)
    int r0 = h - 1; if (r0 < 0) r0 = 0;
    int r2 = h + 1; if (r2 > HH - 1) r2 = HH - 1;
    int row0 = r0 * WW + w, row1 = h * WW + w, row2 = r2 * WW + w;

    const float* xb = x + b * (CC * HH * WW);

    for (int r = 0; r < REP; ++r) {
        int fce = (fc + r) & 15;           // SGPR-uniform per iteration
        int f0  = fce * FCHUNK;
        const float* wbase = wgt + f0 * (CC * 9);    // s_load base

        float dist[FCHUNK];
#pragma unroll
        for (int i = 0; i < FCHUNK; ++i) dist[i] = 0.0f;

#pragma unroll 4
        for (int c = 0; c < CC; ++c) {
            const float* xc = xb + c * (HH * WW);
            float v0 = xc[row0], v1 = xc[row1], v2 = xc[row2];
            float p[9];
            p[0] = DPP_LEFT(v0);  p[1] = v0;  p[2] = DPP_RIGHT(v0);
            p[3] = DPP_LEFT(v1);  p[4] = v1;  p[5] = DPP_RIGHT(v1);
            p[6] = DPP_LEFT(v2);  p[7] = v2;  p[8] = DPP_RIGHT(v2);
#pragma unroll
            for (int fi = 0; fi < FCHUNK; ++fi) {
                const float* wrow = wbase + fi * (CC * 9) + c * 9;  // s_load
#pragma unroll
                for (int k = 0; k < 9; ++k) {
                    float d = p[k] - wrow[k];
                    dist[fi] = fmaxf(dist[fi], fabsf(d));
                }
            }
        }

        float* ob = out + ((b * FF + f0) * HH + h) * WW + w;
#pragma unroll
        for (int fi = 0; fi < FCHUNK; ++fi) {
            ob[fi * (HH * WW)] = dist[fi] + bias[f0 + fi];
        }
    }
}

extern "C" void kernel_launch(void* const* d_in, const int* in_sizes, int n_in,
                              void* d_out, int out_size, void* d_ws, size_t ws_size,
                              hipStream_t stream) {
    const float* x    = (const float*)d_in[0];
    const float* wgt  = (const float*)d_in[1];
    const float* bias = (const float*)d_in[2];
    float* out = (float*)d_out;

    const int total = (FF / FCHUNK) * BB * HH * WW;  // 262144 threads, 1024 blocks
    dist_conv2d_kernel<<<total / 256, 256, 0, stream>>>(x, wgt, bias, out);
}

// Round 10
// 14.748 us; speedup vs baseline: 4.4303x; 4.4303x over previous
//
#include <hip/hip_runtime.h>

// Dist_Conv2D: out[b,f,h,w] = max_{c,i,j} |W[f, c*9+i*3+j] - x_pad[b,c,h+i,w+j]| + bias[f]
// x: (4,16,64,64) f32, W: (64,144) f32, bias: (64,) f32, out: (4,64,64,64) f32
// replicate pad 1 on each side of H,W.
//
// R10: packed-fp32. R9 probe measured VALUBusy ~87% (VALU-issue bound) with
// ~7.4us/rep work + ~6us fixed overhead. Lever: fewer issue slots/element.
//  - Each thread computes TWO h rows (h0 even, h1=h0+1) x 2 filters.
//    For kernel-row i, the (outputA,outputB) x-values are (v_i, v_{i+1}) —
//    consecutive rows — so one v_pk_add_f32 computes both outputs' p-w.
//  - Weight splat {w,w} built in SGPRs (scalar pipe, hidden under VALU).
//  - Max chains: fmax(fmax(acc,|a|),|b|) per component -> v_max3_f32 fusion,
//    4 independent chains (2f x 2h) interleaved for ILP.
// Keep: DPP column neighbors (replicate-pad via bound_ctrl=false), SGPR
// weights (R4), 1024 blocks = 4 waves/SIMD (R9 regime), no min-waves bound.

#define BB 4
#define CC 16
#define HH 64
#define WW 64
#define FF 64
#define FCHUNK 2

typedef float f32x2 __attribute__((ext_vector_type(2)));

#define DPP_LEFT(v)  __int_as_float(__builtin_amdgcn_update_dpp(            \
        __float_as_int(v), __float_as_int(v), 0x138, 0xf, 0xf, false))
#define DPP_RIGHT(v) __int_as_float(__builtin_amdgcn_update_dpp(            \
        __float_as_int(v), __float_as_int(v), 0x130, 0xf, 0xf, false))

// D = P - {w,w} : one packed sub for both h-outputs. w stays scalar (SGPR pair).
#define PKSUB(D, P, WV) do {                                                \
        float _wf = (WV);                                                   \
        unsigned int _wu = __float_as_uint(_wf);                            \
        unsigned long long _w2 =                                            \
            ((unsigned long long)_wu << 32) | (unsigned long long)_wu;      \
        asm("v_pk_add_f32 %0, %1, %2 neg_lo:[0,1] neg_hi:[0,1]"             \
            : "=v"(D) : "v"(P), "s"(_w2));                                  \
    } while (0)

__global__ __launch_bounds__(256) void dist_conv2d_kernel(
    const float* __restrict__ x,
    const float* __restrict__ wgt,
    const float* __restrict__ bias,
    float* __restrict__ out) {
    // 256 threads = hp_lo(2) | w(6); blockIdx bits: fc(5) | b(2) | hp_hi(3)
    int w     = threadIdx.x & 63;          // lane id
    int hp_lo = threadIdx.x >> 6;          // 0..3
    int hp_hi = blockIdx.x & 7;            // 0..7
    int b     = (blockIdx.x >> 3) & 3;     // SGPR
    int fc    = blockIdx.x >> 5;           // SGPR, 0..31
    int f0    = fc * FCHUNK;               // SGPR

    int hp = hp_hi * 4 + hp_lo;            // 0..31
    int h0 = hp * 2;                       // even
    int h1 = h0 + 1;                       // odd

    // replicate-pad clamped outer rows (h0-1 underflows only at 0; h1+1 overflows only at 63)
    int rt = (h0 == 0) ? 0 : h0 - 1;
    int rb = (h1 == HH - 1) ? HH - 1 : h1 + 1;
    int o_t = rt * WW + w, o_a = h0 * WW + w, o_b = h1 * WW + w, o_c = rb * WW + w;

    const float* xb    = x + b * (CC * HH * WW);
    const float* wbase = wgt + f0 * (CC * 9);        // SGPR base -> s_load

    f32x2 acc[FCHUNK];                     // .x = output(h0), .y = output(h1)
#pragma unroll
    for (int i = 0; i < FCHUNK; ++i) acc[i] = (f32x2)(0.0f, 0.0f);

#pragma unroll 4
    for (int c = 0; c < CC; ++c) {
        const float* xc = xb + c * (HH * WW);
        float va = xc[o_t], vb = xc[o_a], vc_ = xc[o_b], vd = xc[o_c];
        // center pairs per kernel-row i: (x-row for out h0, x-row for out h1)
        f32x2 cp0, cp1, cp2, lp0, lp1, lp2, rp0, rp1, rp2;
        cp0.x = va;  cp0.y = vb;
        cp1.x = vb;  cp1.y = vc_;
        cp2.x = vc_; cp2.y = vd;
        lp0.x = DPP_LEFT(cp0.x);  lp0.y = DPP_LEFT(cp0.y);
        lp1.x = DPP_LEFT(cp1.x);  lp1.y = DPP_LEFT(cp1.y);
        lp2.x = DPP_LEFT(cp2.x);  lp2.y = DPP_LEFT(cp2.y);
        rp0.x = DPP_RIGHT(cp0.x); rp0.y = DPP_RIGHT(cp0.y);
        rp1.x = DPP_RIGHT(cp1.x); rp1.y = DPP_RIGHT(cp1.y);
        rp2.x = DPP_RIGHT(cp2.x); rp2.y = DPP_RIGHT(cp2.y);

#pragma unroll
        for (int fi = 0; fi < FCHUNK; ++fi) {
            const float* wr = wbase + fi * (CC * 9) + c * 9;   // uniform -> s_load
            f32x2 d0, d1, d2, d3, d4, d5, d6, d7, d8;
            PKSUB(d0, lp0, wr[0]); PKSUB(d1, cp0, wr[1]); PKSUB(d2, rp0, wr[2]);
            PKSUB(d3, lp1, wr[3]); PKSUB(d4, cp1, wr[4]); PKSUB(d5, rp1, wr[5]);
            PKSUB(d6, lp2, wr[6]); PKSUB(d7, cp2, wr[7]); PKSUB(d8, rp2, wr[8]);
            // fusion-friendly max3 pairs, x/y chains interleaved (independent)
            acc[fi].x = fmaxf(fmaxf(acc[fi].x, fabsf(d0.x)), fabsf(d1.x));
            acc[fi].y = fmaxf(fmaxf(acc[fi].y, fabsf(d0.y)), fabsf(d1.y));
            acc[fi].x = fmaxf(fmaxf(acc[fi].x, fabsf(d2.x)), fabsf(d3.x));
            acc[fi].y = fmaxf(fmaxf(acc[fi].y, fabsf(d2.y)), fabsf(d3.y));
            acc[fi].x = fmaxf(fmaxf(acc[fi].x, fabsf(d4.x)), fabsf(d5.x));
            acc[fi].y = fmaxf(fmaxf(acc[fi].y, fabsf(d4.y)), fabsf(d5.y));
            acc[fi].x = fmaxf(fmaxf(acc[fi].x, fabsf(d6.x)), fabsf(d7.x));
            acc[fi].y = fmaxf(fmaxf(acc[fi].y, fabsf(d6.y)), fabsf(d7.y));
            acc[fi].x = fmaxf(acc[fi].x, fabsf(d8.x));
            acc[fi].y = fmaxf(acc[fi].y, fabsf(d8.y));
        }
    }

#pragma unroll
    for (int fi = 0; fi < FCHUNK; ++fi) {
        float bv = bias[f0 + fi];                              // s_load
        float* ob = out + ((b * FF + f0 + fi) * HH) * WW + w;
        ob[h0 * WW] = acc[fi].x + bv;
        ob[h1 * WW] = acc[fi].y + bv;
    }
}

extern "C" void kernel_launch(void* const* d_in, const int* in_sizes, int n_in,
                              void* d_out, int out_size, void* d_ws, size_t ws_size,
                              hipStream_t stream) {
    const float* x    = (const float*)d_in[0];
    const float* wgt  = (const float*)d_in[1];
    const float* bias = (const float*)d_in[2];
    float* out = (float*)d_out;

    // blocks = fc(32) * b(4) * hp_hi(8) = 1024; 256 threads each
    dist_conv2d_kernel<<<1024, 256, 0, stream>>>(x, wgt, bias, out);
}

// Round 11
// 14.121 us; speedup vs baseline: 4.6271x; 1.0444x over previous
//
#include <hip/hip_runtime.h>

// Dist_Conv2D: out[b,f,h,w] = max_{c,i,j} |W[f, c*9+i*3+j] - x_pad[b,c,h+i,w+j]| + bias[f]
// x: (4,16,64,64) f32, W: (64,144) f32, bias: (64,) f32, out: (4,64,64,64) f32
// replicate pad 1 each side of H,W.
//
// R11: instruction-count cut in PLAIN C (no inline asm — R8/R10 showed asm
// variants lose to clang's own scheduling/fusion).
//  - fmaxf(fmaxf(acc,fabsf(a)),fabsf(b)) -> clang fuses to v_max3_f32 with
//    |.| input modifiers: 5 max-instrs per 9 elems (was 9).
//  - patch paired into f32x2 halves AT LOAD/DPP TIME (loads + dpp movs write
//    pair halves directly, zero extra movs): A=(p0,p1) B=(p2,p3) C=(p4,p5)
//    D=(p6,p7), solo p8. Weight pairs are memory-adjacent -> f32x2 sub lowers
//    to v_pk_add_f32 neg: 5 sub-instrs per 9 elems (was 9).
//  Core per (c,fi): 18 -> 10 instrs. Everything else = R5 (13.42us best).
// Keep: SGPR-provable f0 (R4), FCHUNK=4, no min-waves bound (R2 lesson),
// DPP replicate-pad boundary (bound_ctrl=false keeps own value at w=0/63).

#define BB 4
#define CC 16
#define HH 64
#define WW 64
#define FF 64
#define FCHUNK 4

typedef float f32x2 __attribute__((ext_vector_type(2)));

#define DPP_LEFT(v)  __int_as_float(__builtin_amdgcn_update_dpp(            \
        __float_as_int(v), __float_as_int(v), 0x138, 0xf, 0xf, false))
#define DPP_RIGHT(v) __int_as_float(__builtin_amdgcn_update_dpp(            \
        __float_as_int(v), __float_as_int(v), 0x130, 0xf, 0xf, false))

__global__ __launch_bounds__(256) void dist_conv2d_kernel(
    const float* __restrict__ x,
    const float* __restrict__ wgt,
    const float* __restrict__ bias,
    float* __restrict__ out) {
    // block = 256 threads = (h_lo(2) | w(6)); blockIdx bits: fc(4)|b(2)|h_hi(4)
    int w  = threadIdx.x & 63;             // lane id
    int h  = ((blockIdx.x & 15) << 2) | (threadIdx.x >> 6);
    int b  = (blockIdx.x >> 4) & 3;        // SGPR
    int fc = blockIdx.x >> 6;              // SGPR, 0..15
    int f0 = fc * FCHUNK;                  // SGPR

    // replicate-pad clamped row indices (columns via DPP boundary rule)
    int r0 = h - 1; if (r0 < 0) r0 = 0;
    int r2 = h + 1; if (r2 > HH - 1) r2 = HH - 1;
    int row0 = r0 * WW + w, row1 = h * WW + w, row2 = r2 * WW + w;

    float dist[FCHUNK];
#pragma unroll
    for (int i = 0; i < FCHUNK; ++i) dist[i] = 0.0f;

    const float* xb    = x + b * (CC * HH * WW);
    const float* wbase = wgt + f0 * (CC * 9);        // SGPR base -> s_load

#pragma unroll 4
    for (int c = 0; c < CC; ++c) {
        const float* xc = xb + c * (HH * WW);
        // patch pairs, k-order (i*3+j): A=(p0,p1) B=(p2,p3) C=(p4,p5) D=(p6,p7), p8 solo.
        // loads and DPP movs write pair halves directly — no extra movs.
        f32x2 A, B, C, D;
        A.y = xc[row0];            // v0 = center row0  -> p1
        C.x = xc[row1];            // v1 = center row1  -> p4
        D.y = xc[row2];            // v2 = center row2  -> p7
        A.x = DPP_LEFT(A.y);       // p0
        B.x = DPP_RIGHT(A.y);      // p2
        B.y = DPP_LEFT(C.x);       // p3
        C.y = DPP_RIGHT(C.x);      // p5
        D.x = DPP_LEFT(D.y);       // p6
        float p8 = DPP_RIGHT(D.y); // p8

#pragma unroll
        for (int fi = 0; fi < FCHUNK; ++fi) {
            const float* wr = wbase + fi * (CC * 9) + c * 9;   // uniform -> s_load
            f32x2 w01, w23, w45, w67;
            w01.x = wr[0]; w01.y = wr[1];
            w23.x = wr[2]; w23.y = wr[3];
            w45.x = wr[4]; w45.y = wr[5];
            w67.x = wr[6]; w67.y = wr[7];
            f32x2 dA = A - w01;    // v_pk_add_f32 (neg)
            f32x2 dB = B - w23;
            f32x2 dC = C - w45;
            f32x2 dD = D - w67;
            float d8 = p8 - wr[8];
            float a = dist[fi];
            a = fmaxf(fmaxf(a, fabsf(dA.x)), fabsf(dA.y));   // v_max3 |.| |.|
            a = fmaxf(fmaxf(a, fabsf(dB.x)), fabsf(dB.y));
            a = fmaxf(fmaxf(a, fabsf(dC.x)), fabsf(dC.y));
            a = fmaxf(fmaxf(a, fabsf(dD.x)), fabsf(dD.y));
            a = fmaxf(a, fabsf(d8));
            dist[fi] = a;
        }
    }

    float* ob = out + ((b * FF + f0) * HH + h) * WW + w;
#pragma unroll
    for (int fi = 0; fi < FCHUNK; ++fi) {
        ob[fi * (HH * WW)] = dist[fi] + bias[f0 + fi];   // bias: s_load
    }
}

extern "C" void kernel_launch(void* const* d_in, const int* in_sizes, int n_in,
                              void* d_out, int out_size, void* d_ws, size_t ws_size,
                              hipStream_t stream) {
    const float* x    = (const float*)d_in[0];
    const float* wgt  = (const float*)d_in[1];
    const float* bias = (const float*)d_in[2];
    float* out = (float*)d_out;

    const int total = (FF / FCHUNK) * BB * HH * WW;  // 262144 threads, 1024 blocks
    dist_conv2d_kernel<<<total / 256, 256, 0, stream>>>(x, wgt, bias, out);
}

// Round 12
// 13.811 us; speedup vs baseline: 4.7307x; 1.0224x over previous
//
#include <hip/hip_runtime.h>

// Dist_Conv2D: out[b,f,h,w] = max_{c,i,j} |W[f, c*9+i*3+j] - x_pad[b,c,h+i,w+j]| + bias[f]
// x: (4,16,64,64) f32, W: (64,144) f32, bias: (64,) f32, out: (4,64,64,64) f32
// replicate pad 1 each side of H,W.
//
// R12: lift the register cap. R9 probe revealed VGPR_Count=32 (clang default
// occupancy heuristic) -> register-starved codegen: ~800 extra mov slots/rep,
// no load hoisting (why R7's full unroll was null), every packing "win" eaten
// by churn (R8/R10/R11 regressions). __launch_bounds__(256,2) caps VGPR at
// 128 (16 waves/CU capacity — we launch 16/CU, zero occupancy loss; R2's
// spill was cap=64 with a ~100-reg structure). Body = R7: full c-unroll so
// clang can hoist all 48 x-loads (overlaps the ~6us cold-miss intercept
// measured by the R9 8x-rep fit), DPP column neighbors, SGPR weights.

#define BB 4
#define CC 16
#define HH 64
#define WW 64
#define FF 64
#define FCHUNK 4

#define DPP_LEFT(v)  __int_as_float(__builtin_amdgcn_update_dpp(            \
        __float_as_int(v), __float_as_int(v), 0x138, 0xf, 0xf, false))
#define DPP_RIGHT(v) __int_as_float(__builtin_amdgcn_update_dpp(            \
        __float_as_int(v), __float_as_int(v), 0x130, 0xf, 0xf, false))

__global__ __launch_bounds__(256, 2) void dist_conv2d_kernel(
    const float* __restrict__ x,
    const float* __restrict__ wgt,
    const float* __restrict__ bias,
    float* __restrict__ out) {
    // block = 256 threads = (h_lo(2) | w(6)); blockIdx bits: fc(4)|b(2)|h_hi(4)
    int w  = threadIdx.x & 63;             // lane id
    int h  = ((blockIdx.x & 15) << 2) | (threadIdx.x >> 6);
    int b  = (blockIdx.x >> 4) & 3;        // SGPR
    int fc = blockIdx.x >> 6;              // SGPR, 0..15
    int f0 = fc * FCHUNK;                  // SGPR

    // replicate-pad clamped row indices (columns via DPP boundary rule)
    int r0 = h - 1; if (r0 < 0) r0 = 0;
    int r2 = h + 1; if (r2 > HH - 1) r2 = HH - 1;
    int row0 = r0 * WW + w, row1 = h * WW + w, row2 = r2 * WW + w;

    float dist[FCHUNK];
#pragma unroll
    for (int i = 0; i < FCHUNK; ++i) dist[i] = 0.0f;

    const float* xb    = x + b * (CC * HH * WW);
    const float* wbase = wgt + f0 * (CC * 9);        // SGPR base -> s_load

#pragma unroll
    for (int c = 0; c < CC; ++c) {
        const float* xc = xb + c * (HH * WW);
        float v0 = xc[row0], v1 = xc[row1], v2 = xc[row2];   // 3 loads/channel
        float p[9];
        p[0] = DPP_LEFT(v0);  p[1] = v0;  p[2] = DPP_RIGHT(v0);
        p[3] = DPP_LEFT(v1);  p[4] = v1;  p[5] = DPP_RIGHT(v1);
        p[6] = DPP_LEFT(v2);  p[7] = v2;  p[8] = DPP_RIGHT(v2);
#pragma unroll
        for (int fi = 0; fi < FCHUNK; ++fi) {
            const float* wrow = wbase + fi * (CC * 9) + c * 9;   // uniform -> s_load
#pragma unroll
            for (int k = 0; k < 9; ++k) {
                float d = p[k] - wrow[k];
                dist[fi] = fmaxf(dist[fi], fabsf(d));
            }
        }
    }

    float* ob = out + ((b * FF + f0) * HH + h) * WW + w;
#pragma unroll
    for (int fi = 0; fi < FCHUNK; ++fi) {
        ob[fi * (HH * WW)] = dist[fi] + bias[f0 + fi];   // bias: s_load
    }
}

extern "C" void kernel_launch(void* const* d_in, const int* in_sizes, int n_in,
                              void* d_out, int out_size, void* d_ws, size_t ws_size,
                              hipStream_t stream) {
    const float* x    = (const float*)d_in[0];
    const float* wgt  = (const float*)d_in[1];
    const float* bias = (const float*)d_in[2];
    float* out = (float*)d_out;

    const int total = (FF / FCHUNK) * BB * HH * WW;  // 262144 threads, 1024 blocks
    dist_conv2d_kernel<<<total / 256, 256, 0, stream>>>(x, wgt, bias, out);
}